// Round 1
// baseline (4127.210 us; speedup 1.0000x reference)
//
#include <hip/hip_runtime.h>

// Problem constants
constexpr int Bg  = 1024;          // graphs
constexpr int Sg  = 64;            // nodes per graph
constexpr int EPG = 256;           // edges per graph
constexpr int Nn  = Bg * Sg;       // 65536 nodes
constexpr int Ne  = Bg * EPG;      // 262144 edges
constexpr int D   = 128;
constexpr int NH  = 4;             // attention heads
constexpr float NEG = 0.2f;

constexpr int CHUNK_G = 512;               // graphs per GAT-layer chunk
constexpr int CHUNK_N = CHUNK_G * Sg;      // 32768 nodes

static __device__ __forceinline__ unsigned fenc(float f) {
    unsigned u = __float_as_uint(f);
    return (u & 0x80000000u) ? ~u : (u | 0x80000000u);
}
static __device__ __forceinline__ float fdec(unsigned k) {
    unsigned u = (k & 0x80000000u) ? (k ^ 0x80000000u) : ~k;
    return __uint_as_float(u);
}

// ---------------- layer-0 projections (K=9) ----------------
__global__ __launch_bounds__(256)
void proj0(const float* __restrict__ x, const float* __restrict__ Wl,
           const float* __restrict__ Wr, const float* __restrict__ bl,
           const float* __restrict__ br, float* __restrict__ xl0,
           float* __restrict__ xr0) {
    int t = blockIdx.x * 256 + threadIdx.x;     // Nn*128 threads
    int n = t >> 7, j = t & 127;
    float xv[9];
#pragma unroll
    for (int k = 0; k < 9; ++k) xv[k] = x[n * 9 + k];
    float al = bl[j], ar = br[j];
#pragma unroll
    for (int k = 0; k < 9; ++k) {
        al = fmaf(xv[k], Wl[k * 128 + j], al);
        ar = fmaf(xv[k], Wr[k * 128 + j], ar);
    }
    xl0[t] = al;
    xr0[t] = ar;
}

// ---------------- fp32 GEMM, K=128, 128x128 tile, 8x8 micro ----------------
// C[M][NC] = epi( act(A[M][128]) @ W[128][NC] + bias )
// EPI 0: C = acc + bias     EPI 1 (NC==128): C = (res + acc + bias) * 0.5
template<bool RELU, int EPI>
__global__ __launch_bounds__(256, 2)
void gemm_k128(const float* __restrict__ A, const float* __restrict__ W,
               const float* __restrict__ bias, const float* __restrict__ res,
               float* __restrict__ C, int NC) {
    __shared__ float At[64 * 132];   // [k_local][row 0..127, pad 132]
    __shared__ float Ws[64 * 132];   // [k_local][col 0..127, pad 132]
    const int t  = threadIdx.x;
    const int r0 = blockIdx.y * 128, c0 = blockIdx.x * 128;
    const int ty = t >> 4, tx = t & 15;
    float acc[8][8] = {};

    for (int kc = 0; kc < 2; ++kc) {
        // stage A (128 rows x 64 k) transposed
#pragma unroll
        for (int i = 0; i < 8; ++i) {
            int f  = t + i * 256;            // 2048 float4
            int r  = f >> 4;                 // 16 float4 per row
            int c4 = (f & 15) << 2;
            float4 v = *reinterpret_cast<const float4*>(
                &A[(size_t)(r0 + r) * 128 + kc * 64 + c4]);
            if (RELU) {
                v.x = fmaxf(v.x, 0.f); v.y = fmaxf(v.y, 0.f);
                v.z = fmaxf(v.z, 0.f); v.w = fmaxf(v.w, 0.f);
            }
            At[(c4 + 0) * 132 + r] = v.x;
            At[(c4 + 1) * 132 + r] = v.y;
            At[(c4 + 2) * 132 + r] = v.z;
            At[(c4 + 3) * 132 + r] = v.w;
        }
        // stage W (64 k x 128 cols)
#pragma unroll
        for (int i = 0; i < 8; ++i) {
            int f  = t + i * 256;
            int wr = f >> 5;                 // 32 float4 per k-row
            int c4 = (f & 31) << 2;
            float4 v = *reinterpret_cast<const float4*>(
                &W[(size_t)(kc * 64 + wr) * NC + c0 + c4]);
            *reinterpret_cast<float4*>(&Ws[wr * 132 + c4]) = v;
        }
        __syncthreads();
#pragma unroll 4
        for (int k = 0; k < 64; ++k) {
            float4 a0 = *reinterpret_cast<const float4*>(&At[k * 132 + ty * 8]);
            float4 a1 = *reinterpret_cast<const float4*>(&At[k * 132 + ty * 8 + 4]);
            float4 b0 = *reinterpret_cast<const float4*>(&Ws[k * 132 + tx * 8]);
            float4 b1 = *reinterpret_cast<const float4*>(&Ws[k * 132 + tx * 8 + 4]);
            float av[8] = {a0.x, a0.y, a0.z, a0.w, a1.x, a1.y, a1.z, a1.w};
            float bv[8] = {b0.x, b0.y, b0.z, b0.w, b1.x, b1.y, b1.z, b1.w};
#pragma unroll
            for (int i = 0; i < 8; ++i)
#pragma unroll
                for (int j = 0; j < 8; ++j)
                    acc[i][j] = fmaf(av[i], bv[j], acc[i][j]);
        }
        __syncthreads();
    }
    // epilogue
#pragma unroll
    for (int i = 0; i < 8; ++i) {
        int r = r0 + ty * 8 + i;
#pragma unroll
        for (int jj = 0; jj < 2; ++jj) {
            int c = c0 + tx * 8 + jj * 4;
            float4 v;
            v.x = acc[i][jj * 4 + 0] + bias[c + 0];
            v.y = acc[i][jj * 4 + 1] + bias[c + 1];
            v.z = acc[i][jj * 4 + 2] + bias[c + 2];
            v.w = acc[i][jj * 4 + 3] + bias[c + 3];
            if (EPI == 1) {
                const float4 rr = *reinterpret_cast<const float4*>(
                    &res[(size_t)r * 128 + c]);
                v.x = (v.x + rr.x) * 0.5f; v.y = (v.y + rr.y) * 0.5f;
                v.z = (v.z + rr.z) * 0.5f; v.w = (v.w + rr.w) * 0.5f;
            }
            *reinterpret_cast<float4*>(&C[(size_t)r * NC + c]) = v;
        }
    }
}

// ---------------- GATv2 edge kernel: one graph per block ----------------
// EPI 0: hout = out + bias             (layer 0, HEADS=1, concat)
// EPI 1: hout = (out/H + bias + hres)/2 (layers 1..3, HEADS=4, mean)
template<int HEADS, int EPI>
__global__ __launch_bounds__(512, 1)
void gat_edge(const float* __restrict__ xl, const float* __restrict__ xr,
              const int* __restrict__ ei, const float* __restrict__ ea,
              const float* __restrict__ We, const float* __restrict__ att,
              const float* __restrict__ bias, const float* __restrict__ hres,
              float* __restrict__ hout, int g0) {
    constexpr int WROW = HEADS * 128;
    __shared__ float xls[64 * 128];
    __shared__ float xrs[64 * 128];
    __shared__ float outs[64 * 128];
    __shared__ float logit[EPG];            // then alpha
    __shared__ int   se[EPG], de[EPG];
    __shared__ unsigned nmax[64];
    __shared__ float nden[64];

    const int g = g0 + blockIdx.x;
    const int t = threadIdx.x, lane = t & 63, wave = t >> 6;   // 8 waves

    for (int i = t; i < 64 * 128; i += 512) outs[i] = 0.f;
    if (t < EPG) {
        se[t] = ei[g * EPG + t] - g * 64;          // src local
        de[t] = ei[Ne + g * EPG + t] - g * 64;     // dst local
    }
    __syncthreads();

    for (int hh = 0; hh < HEADS; ++hh) {
        // stage per-head xl / xr tiles (64 x 128)
#pragma unroll
        for (int i = 0; i < 4; ++i) {
            int f  = t + i * 512;                  // 2048 float4
            int r  = f >> 5;
            int c4 = (f & 31) << 2;
            size_t nl = (size_t)((g - g0) * 64 + r);
            *reinterpret_cast<float4*>(&xls[r * 128 + c4]) =
                *reinterpret_cast<const float4*>(&xl[nl * WROW + hh * 128 + c4]);
            *reinterpret_cast<float4*>(&xrs[r * 128 + c4]) =
                *reinterpret_cast<const float4*>(&xr[nl * WROW + hh * 128 + c4]);
        }
        if (t < 64) { nmax[t] = 0u; nden[t] = 0.f; }
        __syncthreads();

        // per-lane constants for this head
        const float a1 = att[hh * 128 + lane];
        const float a2 = att[hh * 128 + 64 + lane];
        float we1[3], we2[3];
#pragma unroll
        for (int k = 0; k < 3; ++k) {
            we1[k] = We[k * WROW + hh * 128 + lane];
            we2[k] = We[k * WROW + hh * 128 + 64 + lane];
        }

        // logits: one wave per edge
        for (int e = wave; e < EPG; e += 8) {
            int s_ = se[e], d_ = de[e];
            float e0 = ea[(size_t)(g * EPG + e) * 3 + 0];
            float e1 = ea[(size_t)(g * EPG + e) * 3 + 1];
            float e2 = ea[(size_t)(g * EPG + e) * 3 + 2];
            float m1 = xls[s_ * 128 + lane] + xrs[d_ * 128 + lane]
                       + e0 * we1[0] + e1 * we1[1] + e2 * we1[2];
            float m2 = xls[s_ * 128 + 64 + lane] + xrs[d_ * 128 + 64 + lane]
                       + e0 * we2[0] + e1 * we2[1] + e2 * we2[2];
            m1 = m1 > 0.f ? m1 : NEG * m1;
            m2 = m2 > 0.f ? m2 : NEG * m2;
            float r = m1 * a1 + m2 * a2;
#pragma unroll
            for (int o = 32; o; o >>= 1) r += __shfl_xor(r, o, 64);
            if (lane == 0) logit[e] = r;
        }
        __syncthreads();

        // segment softmax over dst
        if (t < EPG) atomicMax(&nmax[de[t]], fenc(logit[t]));
        __syncthreads();
        float ex = 0.f;
        if (t < EPG) {
            ex = __expf(logit[t] - fdec(nmax[de[t]]));
            atomicAdd(&nden[de[t]], ex);
        }
        __syncthreads();
        if (t < EPG) logit[t] = ex / nden[de[t]];   // alpha
        __syncthreads();

        // scatter: out[dst] += alpha * xl[src]
        for (int e = wave; e < EPG; e += 8) {
            int s_ = se[e], d_ = de[e];
            float a = logit[e];
            atomicAdd(&outs[d_ * 128 + lane],      a * xls[s_ * 128 + lane]);
            atomicAdd(&outs[d_ * 128 + 64 + lane], a * xls[s_ * 128 + 64 + lane]);
        }
        __syncthreads();
    }

    // epilogue
    constexpr float inv = 1.0f / (float)HEADS;
    for (int i = t; i < 64 * 128; i += 512) {
        int r = i >> 7, c = i & 127;
        size_t gi = (size_t)(g * 64 + r) * 128 + c;
        float v = outs[i] * inv + bias[c];
        if (EPI == 1) v = (v + hres[gi]) * 0.5f;
        hout[gi] = v;
    }
}

// ---------------- dense attention: one graph per block ----------------
__global__ __launch_bounds__(256, 3)
void attn_k(const float* __restrict__ q, const float* __restrict__ k,
            const float* __restrict__ v, float* __restrict__ o) {
    __shared__ float qs[64 * 33], ks[64 * 33], vs[64 * 33];
    __shared__ float al[64 * 64];
    const int g = blockIdx.x, t = threadIdx.x, lane = t & 63, wave = t >> 6;

    for (int hh = 0; hh < NH; ++hh) {
        for (int i = t; i < 2048; i += 256) {
            int r = i >> 5, d = i & 31;
            size_t gi = (size_t)(g * 64 + r) * 128 + hh * 32 + d;
            qs[r * 33 + d] = q[gi];
            ks[r * 33 + d] = k[gi];
            vs[r * 33 + d] = v[gi];
        }
        __syncthreads();
        // scores + softmax: wave handles 16 query rows; lane = key index
        for (int qi = wave * 16; qi < wave * 16 + 16; ++qi) {
            float s = 0.f;
#pragma unroll
            for (int d = 0; d < 32; ++d) s = fmaf(qs[qi * 33 + d], ks[lane * 33 + d], s);
            s *= 0.17677669529663687f;      // 1/sqrt(32)
            float mx = s;
#pragma unroll
            for (int o_ = 32; o_; o_ >>= 1) mx = fmaxf(mx, __shfl_xor(mx, o_, 64));
            float e = __expf(s - mx);
            float den = e;
#pragma unroll
            for (int o_ = 32; o_; o_ >>= 1) den += __shfl_xor(den, o_, 64);
            al[qi * 64 + lane] = e / den;
        }
        __syncthreads();
        // PV: thread -> (qi, d)
        int d = t & 31, q0 = t >> 5;
        for (int it = 0; it < 8; ++it) {
            int qi = q0 + it * 8;
            float acc = 0.f;
#pragma unroll 8
            for (int kj = 0; kj < 64; ++kj)
                acc = fmaf(al[qi * 64 + kj], vs[kj * 33 + d], acc);
            o[(size_t)(g * 64 + qi) * 128 + hh * 32 + d] = acc;
        }
        __syncthreads();
    }
}

// ---------------- launch ----------------
extern "C" void kernel_launch(void* const* d_in, const int* in_sizes, int n_in,
                              void* d_out, int out_size, void* d_ws, size_t ws_size,
                              hipStream_t stream) {
    const float* x     = (const float*)d_in[0];
    const int*   ei    = (const int*)d_in[1];
    const float* ea    = (const float*)d_in[2];
    // d_in[3] = batch (unused; layout is implied)
    const float* g0Wl  = (const float*)d_in[4];
    const float* g0Wr  = (const float*)d_in[5];
    const float* g0bl  = (const float*)d_in[6];
    const float* g0br  = (const float*)d_in[7];
    const float* g0We  = (const float*)d_in[8];
    const float* g0att = (const float*)d_in[9];
    const float* g0bias= (const float*)d_in[10];
    const float* gWl   = (const float*)d_in[11];
    const float* gWr   = (const float*)d_in[12];
    const float* gbl   = (const float*)d_in[13];
    const float* gbr   = (const float*)d_in[14];
    const float* gWe   = (const float*)d_in[15];
    const float* gatt  = (const float*)d_in[16];
    const float* gbias = (const float*)d_in[17];
    const float* Wq    = (const float*)d_in[18];
    const float* Wk    = (const float*)d_in[19];
    const float* Wv    = (const float*)d_in[20];
    const float* bq    = (const float*)d_in[21];
    const float* bk    = (const float*)d_in[22];
    const float* bv    = (const float*)d_in[23];
    const float* Wo    = (const float*)d_in[24];
    const float* bo    = (const float*)d_in[25];
    float* out = (float*)d_out;
    float* ws  = (float*)d_ws;

    float* h   = ws;                                   // Nn*128
    float* xlb = ws + (size_t)Nn * 128;                // CHUNK_N*512
    float* xrb = xlb + (size_t)CHUNK_N * 512;          // CHUNK_N*512
    // attention-phase reuse of the xl/xr regions:
    float* qb = xlb;
    float* kb = xlb + (size_t)Nn * 128;
    float* vb = xrb;
    float* ob = xrb + (size_t)Nn * 128;

    // ---- layer 0 (heads=1, concat) ----
    proj0<<<Nn * 128 / 256, 256, 0, stream>>>(x, g0Wl, g0Wr, g0bl, g0br, xlb, xrb);
    gat_edge<1, 0><<<Bg, 512, 0, stream>>>(xlb, xrb, ei, ea, g0We, g0att,
                                           g0bias, nullptr, h, 0);

    // ---- layers 1..3 (heads=4, mean, residual) ----
    for (int i = 0; i < 3; ++i) {
        for (int c = 0; c < 2; ++c) {
            const float* Ain = h + (size_t)c * CHUNK_N * 128;
            dim3 grid(512 / 128, CHUNK_N / 128);
            gemm_k128<true, 0><<<grid, 256, 0, stream>>>(
                Ain, gWl + (size_t)i * 128 * 512, gbl + i * 512, nullptr, xlb, 512);
            gemm_k128<true, 0><<<grid, 256, 0, stream>>>(
                Ain, gWr + (size_t)i * 128 * 512, gbr + i * 512, nullptr, xrb, 512);
            gat_edge<4, 1><<<CHUNK_G, 512, 0, stream>>>(
                xlb, xrb, ei, ea, gWe + (size_t)i * 3 * 512,
                gatt + (size_t)i * 4 * 128, gbias + i * 128, h, h, c * CHUNK_G);
        }
    }

    // ---- dense attention over graphs ----
    {
        dim3 grid(1, Nn / 128);
        gemm_k128<false, 0><<<grid, 256, 0, stream>>>(h, Wq, bq, nullptr, qb, 128);
        gemm_k128<false, 0><<<grid, 256, 0, stream>>>(h, Wk, bk, nullptr, kb, 128);
        gemm_k128<false, 0><<<grid, 256, 0, stream>>>(h, Wv, bv, nullptr, vb, 128);
        attn_k<<<Bg, 256, 0, stream>>>(qb, kb, vb, ob);
        gemm_k128<false, 1><<<grid, 256, 0, stream>>>(ob, Wo, bo, h, out, 128);
    }
}

// Round 3
// 1782.471 us; speedup vs baseline: 2.3154x; 2.3154x over previous
//
#include <hip/hip_runtime.h>

// Problem constants
constexpr int Bg  = 1024;          // graphs
constexpr int Sg  = 64;            // nodes per graph
constexpr int EPG = 256;           // edges per graph
constexpr int Nn  = Bg * Sg;       // 65536 nodes
constexpr int Ne  = Bg * EPG;      // 262144 edges
constexpr int NH  = 4;             // attention heads
constexpr float NEG = 0.2f;

constexpr int CHUNK_G = 512;               // graphs per GAT-layer chunk
constexpr int CHUNK_N = CHUNK_G * Sg;      // 32768 nodes

static __device__ __forceinline__ unsigned fenc(float f) {
    unsigned u = __float_as_uint(f);
    return (u & 0x80000000u) ? ~u : (u | 0x80000000u);
}
static __device__ __forceinline__ float fdec(unsigned k) {
    unsigned u = (k & 0x80000000u) ? (k ^ 0x80000000u) : ~k;
    return __uint_as_float(u);
}

// ---------------- layer-0 projections (K=9) ----------------
__global__ __launch_bounds__(256)
void proj0(const float* __restrict__ x, const float* __restrict__ Wl,
           const float* __restrict__ Wr, const float* __restrict__ bl,
           const float* __restrict__ br, float* __restrict__ xl0,
           float* __restrict__ xr0) {
    int t = blockIdx.x * 256 + threadIdx.x;     // Nn*128 threads
    int n = t >> 7, j = t & 127;
    float xv[9];
#pragma unroll
    for (int k = 0; k < 9; ++k) xv[k] = x[n * 9 + k];
    float al = bl[j], ar = br[j];
#pragma unroll
    for (int k = 0; k < 9; ++k) {
        al = fmaf(xv[k], Wl[k * 128 + j], al);
        ar = fmaf(xv[k], Wr[k * 128 + j], ar);
    }
    xl0[t] = al;
    xr0[t] = ar;
}

// ---------------- fp32 GEMM, K=128, 128x128 tile, 8x8 micro ----------------
template<bool RELU, int EPI>
__global__ __launch_bounds__(256, 2)
void gemm_k128(const float* __restrict__ A, const float* __restrict__ W,
               const float* __restrict__ bias, const float* __restrict__ res,
               float* __restrict__ C, int NC) {
    __shared__ float At[64 * 132];   // [k_local][row 0..127, pad 132]
    __shared__ float Ws[64 * 132];   // [k_local][col 0..127, pad 132]
    const int t  = threadIdx.x;
    const int r0 = blockIdx.y * 128, c0 = blockIdx.x * 128;
    const int ty = t >> 4, tx = t & 15;
    float acc[8][8] = {};

    for (int kc = 0; kc < 2; ++kc) {
#pragma unroll
        for (int i = 0; i < 8; ++i) {
            int f  = t + i * 256;            // 2048 float4
            int r  = f >> 4;
            int c4 = (f & 15) << 2;
            float4 v = *reinterpret_cast<const float4*>(
                &A[(size_t)(r0 + r) * 128 + kc * 64 + c4]);
            if (RELU) {
                v.x = fmaxf(v.x, 0.f); v.y = fmaxf(v.y, 0.f);
                v.z = fmaxf(v.z, 0.f); v.w = fmaxf(v.w, 0.f);
            }
            At[(c4 + 0) * 132 + r] = v.x;
            At[(c4 + 1) * 132 + r] = v.y;
            At[(c4 + 2) * 132 + r] = v.z;
            At[(c4 + 3) * 132 + r] = v.w;
        }
#pragma unroll
        for (int i = 0; i < 8; ++i) {
            int f  = t + i * 256;
            int wr = f >> 5;
            int c4 = (f & 31) << 2;
            float4 v = *reinterpret_cast<const float4*>(
                &W[(size_t)(kc * 64 + wr) * NC + c0 + c4]);
            *reinterpret_cast<float4*>(&Ws[wr * 132 + c4]) = v;
        }
        __syncthreads();
#pragma unroll 4
        for (int k = 0; k < 64; ++k) {
            float4 a0 = *reinterpret_cast<const float4*>(&At[k * 132 + ty * 8]);
            float4 a1 = *reinterpret_cast<const float4*>(&At[k * 132 + ty * 8 + 4]);
            float4 b0 = *reinterpret_cast<const float4*>(&Ws[k * 132 + tx * 8]);
            float4 b1 = *reinterpret_cast<const float4*>(&Ws[k * 132 + tx * 8 + 4]);
            float av[8] = {a0.x, a0.y, a0.z, a0.w, a1.x, a1.y, a1.z, a1.w};
            float bv[8] = {b0.x, b0.y, b0.z, b0.w, b1.x, b1.y, b1.z, b1.w};
#pragma unroll
            for (int i = 0; i < 8; ++i)
#pragma unroll
                for (int j = 0; j < 8; ++j)
                    acc[i][j] = fmaf(av[i], bv[j], acc[i][j]);
        }
        __syncthreads();
    }
#pragma unroll
    for (int i = 0; i < 8; ++i) {
        int r = r0 + ty * 8 + i;
#pragma unroll
        for (int jj = 0; jj < 2; ++jj) {
            int c = c0 + tx * 8 + jj * 4;
            float4 v;
            v.x = acc[i][jj * 4 + 0] + bias[c + 0];
            v.y = acc[i][jj * 4 + 1] + bias[c + 1];
            v.z = acc[i][jj * 4 + 2] + bias[c + 2];
            v.w = acc[i][jj * 4 + 3] + bias[c + 3];
            if (EPI == 1) {
                const float4 rr = *reinterpret_cast<const float4*>(
                    &res[(size_t)r * 128 + c]);
                v.x = (v.x + rr.x) * 0.5f; v.y = (v.y + rr.y) * 0.5f;
                v.z = (v.z + rr.z) * 0.5f; v.w = (v.w + rr.w) * 0.5f;
            }
            *reinterpret_cast<float4*>(&C[(size_t)r * NC + c]) = v;
        }
    }
}

// ---------------- GATv2 edge kernel (v2): alpha -> dense P, then P@X ----------------
// One graph per block, 512 threads. Per head:
//   stage xl/xr tiles -> wave-per-edge logits -> LDS segment softmax ->
//   P[src][dst] (aliased over xr tile) -> out += dense P@X GEMM in regs.
// Accumulators live in registers across heads; no LDS scatter atomics.
// EPI 0: hout = acc + bias              (layer 0, HEADS=1)
// EPI 1: hout = (acc/H + bias + hres)/2 (layers 1..3, HEADS=4, mean + residual)
template<int HEADS, int EPI>
__global__ __launch_bounds__(512, 4)
void gat_edge(const float* __restrict__ xl, const float* __restrict__ xr,
              const int* __restrict__ ei, const float* __restrict__ ea,
              const float* __restrict__ We, const float* __restrict__ att,
              const float* __restrict__ bias, const float* __restrict__ hres,
              float* __restrict__ hout, int g0) {
    constexpr int WROW = HEADS * 128;
    constexpr int PST  = 68;   // P row stride (floats): 272B, 16B-aligned rows
    __shared__ __align__(16) float xls[64 * 128];
    __shared__ __align__(16) float xrp[64 * 128];   // xr tile; aliased by P[64][68] after logits
    __shared__ float eas[EPG * 4];
    __shared__ float logit[EPG];
    __shared__ int   se[EPG], de[EPG];
    __shared__ unsigned nmax[64];
    __shared__ float nden[64];

    const int g = g0 + blockIdx.x;
    const int t = threadIdx.x, lane = t & 63, wave = t >> 6;   // 8 waves
    const int rg = (t >> 5) << 2;        // 4 output rows (dst)
    const int cg = (t & 31) << 2;        // 4 output cols

    if (t < EPG) {
        se[t] = ei[g * EPG + t] - g * 64;            // src local
        de[t] = ei[Ne + g * EPG + t] - g * 64;       // dst local
        eas[t * 4 + 0] = ea[(size_t)(g * EPG + t) * 3 + 0];
        eas[t * 4 + 1] = ea[(size_t)(g * EPG + t) * 3 + 1];
        eas[t * 4 + 2] = ea[(size_t)(g * EPG + t) * 3 + 2];
    }

    float acc[4][4] = {};

    for (int hh = 0; hh < HEADS; ++hh) {
        __syncthreads();   // previous P@X / edge-load done before re-staging
        // stage per-head xl / xr tiles (64 x 128)
#pragma unroll
        for (int i = 0; i < 4; ++i) {
            int f  = t + i * 512;                    // 2048 float4
            int r  = f >> 5;
            int c4 = (f & 31) << 2;
            size_t nl = (size_t)((g - g0) * 64 + r);
            *reinterpret_cast<float4*>(&xls[r * 128 + c4]) =
                *reinterpret_cast<const float4*>(&xl[nl * WROW + hh * 128 + c4]);
            *reinterpret_cast<float4*>(&xrp[r * 128 + c4]) =
                *reinterpret_cast<const float4*>(&xr[nl * WROW + hh * 128 + c4]);
        }
        if (t < 64) { nmax[t] = 0u; nden[t] = 0.f; }
        __syncthreads();

        const float a1 = att[hh * 128 + lane];
        const float a2 = att[hh * 128 + 64 + lane];
        float we1[3], we2[3];
#pragma unroll
        for (int k = 0; k < 3; ++k) {
            we1[k] = We[k * WROW + hh * 128 + lane];
            we2[k] = We[k * WROW + hh * 128 + 64 + lane];
        }

        // logits: one wave per edge (lanes = 2 dims each), shfl tree-reduce
        for (int e = wave; e < EPG; e += 8) {
            int s_ = se[e], d_ = de[e];
            float e0 = eas[e * 4 + 0], e1 = eas[e * 4 + 1], e2 = eas[e * 4 + 2];
            float m1 = xls[s_ * 128 + lane] + xrp[d_ * 128 + lane]
                       + e0 * we1[0] + e1 * we1[1] + e2 * we1[2];
            float m2 = xls[s_ * 128 + 64 + lane] + xrp[d_ * 128 + 64 + lane]
                       + e0 * we2[0] + e1 * we2[1] + e2 * we2[2];
            m1 = m1 > 0.f ? m1 : NEG * m1;
            m2 = m2 > 0.f ? m2 : NEG * m2;
            float r = fmaf(m1, a1, m2 * a2);
#pragma unroll
            for (int o = 32; o; o >>= 1) r += __shfl_xor(r, o, 64);
            if (lane == 0) logit[e] = r;
        }
        __syncthreads();

        // xr tile is dead now -> reuse as P[src][dst]
        float* P = xrp;
        for (int i = t; i < 64 * PST; i += 512) P[i] = 0.f;
        if (t < EPG) atomicMax(&nmax[de[t]], fenc(logit[t]));
        __syncthreads();
        float ex = 0.f;
        if (t < EPG) {
            ex = __expf(logit[t] - fdec(nmax[de[t]]));
            atomicAdd(&nden[de[t]], ex);
        }
        __syncthreads();
        if (t < EPG) atomicAdd(&P[se[t] * PST + de[t]], ex / nden[de[t]]);
        __syncthreads();

        // dense P@X: acc[i][j] += sum_k P[k][rg+i] * xls[k][cg+j]
#pragma unroll 4
        for (int k = 0; k < 64; ++k) {
            float4 pv = *reinterpret_cast<const float4*>(&P[k * PST + rg]);
            float4 xv = *reinterpret_cast<const float4*>(&xls[k * 128 + cg]);
            acc[0][0] = fmaf(pv.x, xv.x, acc[0][0]);
            acc[0][1] = fmaf(pv.x, xv.y, acc[0][1]);
            acc[0][2] = fmaf(pv.x, xv.z, acc[0][2]);
            acc[0][3] = fmaf(pv.x, xv.w, acc[0][3]);
            acc[1][0] = fmaf(pv.y, xv.x, acc[1][0]);
            acc[1][1] = fmaf(pv.y, xv.y, acc[1][1]);
            acc[1][2] = fmaf(pv.y, xv.z, acc[1][2]);
            acc[1][3] = fmaf(pv.y, xv.w, acc[1][3]);
            acc[2][0] = fmaf(pv.z, xv.x, acc[2][0]);
            acc[2][1] = fmaf(pv.z, xv.y, acc[2][1]);
            acc[2][2] = fmaf(pv.z, xv.z, acc[2][2]);
            acc[2][3] = fmaf(pv.z, xv.w, acc[2][3]);
            acc[3][0] = fmaf(pv.w, xv.x, acc[3][0]);
            acc[3][1] = fmaf(pv.w, xv.y, acc[3][1]);
            acc[3][2] = fmaf(pv.w, xv.z, acc[3][2]);
            acc[3][3] = fmaf(pv.w, xv.w, acc[3][3]);
        }
    }

    // epilogue from registers
    constexpr float inv = 1.0f / (float)HEADS;
#pragma unroll
    for (int i = 0; i < 4; ++i) {
        int r = rg + i;
        size_t gi = (size_t)(g * 64 + r) * 128 + cg;
        float4 v;
        v.x = acc[i][0] * inv + bias[cg + 0];
        v.y = acc[i][1] * inv + bias[cg + 1];
        v.z = acc[i][2] * inv + bias[cg + 2];
        v.w = acc[i][3] * inv + bias[cg + 3];
        if (EPI == 1) {
            const float4 rr = *reinterpret_cast<const float4*>(&hres[gi]);
            v.x = (v.x + rr.x) * 0.5f; v.y = (v.y + rr.y) * 0.5f;
            v.z = (v.z + rr.z) * 0.5f; v.w = (v.w + rr.w) * 0.5f;
        }
        *reinterpret_cast<float4*>(&hout[gi]) = v;
    }
}

// ---------------- dense attention: one graph per block ----------------
__global__ __launch_bounds__(256, 3)
void attn_k(const float* __restrict__ q, const float* __restrict__ k,
            const float* __restrict__ v, float* __restrict__ o) {
    __shared__ float qs[64 * 33], ks[64 * 33], vs[64 * 33];
    __shared__ float al[64 * 64];
    const int g = blockIdx.x, t = threadIdx.x, lane = t & 63, wave = t >> 6;

    for (int hh = 0; hh < NH; ++hh) {
        for (int i = t; i < 2048; i += 256) {
            int r = i >> 5, d = i & 31;
            size_t gi = (size_t)(g * 64 + r) * 128 + hh * 32 + d;
            qs[r * 33 + d] = q[gi];
            ks[r * 33 + d] = k[gi];
            vs[r * 33 + d] = v[gi];
        }
        __syncthreads();
        for (int qi = wave * 16; qi < wave * 16 + 16; ++qi) {
            float s = 0.f;
#pragma unroll
            for (int d = 0; d < 32; ++d) s = fmaf(qs[qi * 33 + d], ks[lane * 33 + d], s);
            s *= 0.17677669529663687f;      // 1/sqrt(32)
            float mx = s;
#pragma unroll
            for (int o_ = 32; o_; o_ >>= 1) mx = fmaxf(mx, __shfl_xor(mx, o_, 64));
            float e = __expf(s - mx);
            float den = e;
#pragma unroll
            for (int o_ = 32; o_; o_ >>= 1) den += __shfl_xor(den, o_, 64);
            al[qi * 64 + lane] = e / den;
        }
        __syncthreads();
        int d = t & 31, q0 = t >> 5;
        for (int it = 0; it < 8; ++it) {
            int qi = q0 + it * 8;
            float acc = 0.f;
#pragma unroll 8
            for (int kj = 0; kj < 64; ++kj)
                acc = fmaf(al[qi * 64 + kj], vs[kj * 33 + d], acc);
            o[(size_t)(g * 64 + qi) * 128 + hh * 32 + d] = acc;
        }
        __syncthreads();
    }
}

// ---------------- launch ----------------
extern "C" void kernel_launch(void* const* d_in, const int* in_sizes, int n_in,
                              void* d_out, int out_size, void* d_ws, size_t ws_size,
                              hipStream_t stream) {
    const float* x     = (const float*)d_in[0];
    const int*   ei    = (const int*)d_in[1];
    const float* ea    = (const float*)d_in[2];
    const float* g0Wl  = (const float*)d_in[4];
    const float* g0Wr  = (const float*)d_in[5];
    const float* g0bl  = (const float*)d_in[6];
    const float* g0br  = (const float*)d_in[7];
    const float* g0We  = (const float*)d_in[8];
    const float* g0att = (const float*)d_in[9];
    const float* g0bias= (const float*)d_in[10];
    const float* gWl   = (const float*)d_in[11];
    const float* gWr   = (const float*)d_in[12];
    const float* gbl   = (const float*)d_in[13];
    const float* gbr   = (const float*)d_in[14];
    const float* gWe   = (const float*)d_in[15];
    const float* gatt  = (const float*)d_in[16];
    const float* gbias = (const float*)d_in[17];
    const float* Wq    = (const float*)d_in[18];
    const float* Wk    = (const float*)d_in[19];
    const float* Wv    = (const float*)d_in[20];
    const float* bq    = (const float*)d_in[21];
    const float* bk    = (const float*)d_in[22];
    const float* bv    = (const float*)d_in[23];
    const float* Wo    = (const float*)d_in[24];
    const float* bo    = (const float*)d_in[25];
    float* out = (float*)d_out;
    float* ws  = (float*)d_ws;

    float* h   = ws;                                   // Nn*128
    float* xlb = ws + (size_t)Nn * 128;                // CHUNK_N*512
    float* xrb = xlb + (size_t)CHUNK_N * 512;          // CHUNK_N*512
    float* qb = xlb;
    float* kb = xlb + (size_t)Nn * 128;
    float* vb = xrb;
    float* ob = xrb + (size_t)Nn * 128;

    // ---- layer 0 (heads=1, concat) ----
    proj0<<<Nn * 128 / 256, 256, 0, stream>>>(x, g0Wl, g0Wr, g0bl, g0br, xlb, xrb);
    gat_edge<1, 0><<<Bg, 512, 0, stream>>>(xlb, xrb, ei, ea, g0We, g0att,
                                           g0bias, nullptr, h, 0);

    // ---- layers 1..3 (heads=4, mean, residual) ----
    for (int i = 0; i < 3; ++i) {
        for (int c = 0; c < 2; ++c) {
            const float* Ain = h + (size_t)c * CHUNK_N * 128;
            dim3 grid(512 / 128, CHUNK_N / 128);
            gemm_k128<true, 0><<<grid, 256, 0, stream>>>(
                Ain, gWl + (size_t)i * 128 * 512, gbl + i * 512, nullptr, xlb, 512);
            gemm_k128<true, 0><<<grid, 256, 0, stream>>>(
                Ain, gWr + (size_t)i * 128 * 512, gbr + i * 512, nullptr, xrb, 512);
            gat_edge<4, 1><<<CHUNK_G, 512, 0, stream>>>(
                xlb, xrb, ei, ea, gWe + (size_t)i * 3 * 512,
                gatt + (size_t)i * 4 * 128, gbias + i * 128, h, h, c * CHUNK_G);
        }
    }

    // ---- dense attention over graphs ----
    {
        dim3 grid(1, Nn / 128);
        gemm_k128<false, 0><<<grid, 256, 0, stream>>>(h, Wq, bq, nullptr, qb, 128);
        gemm_k128<false, 0><<<grid, 256, 0, stream>>>(h, Wk, bk, nullptr, kb, 128);
        gemm_k128<false, 0><<<grid, 256, 0, stream>>>(h, Wv, bv, nullptr, vb, 128);
        attn_k<<<Bg, 256, 0, stream>>>(qb, kb, vb, ob);
        gemm_k128<false, 1><<<grid, 256, 0, stream>>>(ob, Wo, bo, h, out, 128);
    }
}

// Round 5
// 1217.317 us; speedup vs baseline: 3.3904x; 1.4643x over previous
//
#include <hip/hip_runtime.h>

// Problem constants
constexpr int Bg  = 1024;          // graphs
constexpr int Sg  = 64;            // nodes per graph
constexpr int EPG = 256;           // edges per graph
constexpr int Nn  = Bg * Sg;       // 65536 nodes
constexpr int Ne  = Bg * EPG;      // 262144 edges
constexpr int NH  = 4;             // attention heads
constexpr float NEG = 0.2f;

constexpr int CHUNK_G = 512;               // graphs per GAT-layer chunk
constexpr int CHUNK_N = CHUNK_G * Sg;      // 32768 nodes

typedef float  f32x4  __attribute__((ext_vector_type(4)));
typedef short  s16x8  __attribute__((ext_vector_type(8)));
typedef unsigned short u16x4 __attribute__((ext_vector_type(4)));

static __device__ __forceinline__ unsigned fenc(float f) {
    unsigned u = __float_as_uint(f);
    return (u & 0x80000000u) ? ~u : (u | 0x80000000u);
}
static __device__ __forceinline__ float fdec(unsigned k) {
    unsigned u = (k & 0x80000000u) ? (k ^ 0x80000000u) : ~k;
    return __uint_as_float(u);
}
static __device__ __forceinline__ unsigned short bf16rn(float x) {
    unsigned u = __float_as_uint(x);
    u += 0x7FFFu + ((u >> 16) & 1u);
    return (unsigned short)(u >> 16);
}
static __device__ __forceinline__ float bf16f(unsigned short h) {
    return __uint_as_float((unsigned)h << 16);
}

// ---------------- weight prep: transpose + hi/lo bf16 split ----------------
// Layout in whi/wlo (elements, each matrix stored [n][128] k-contiguous):
//   seg 0..5 : gWl0,gWr0,gWl1,gWr1,gWl2,gWr2  (65536 each, NC=512)
//   seg 6..9 : Wq,Wk,Wv,Wo                    (16384 each, NC=128)
__global__ __launch_bounds__(256)
void wprep(const float* __restrict__ gWl, const float* __restrict__ gWr,
           const float* __restrict__ Wq, const float* __restrict__ Wk,
           const float* __restrict__ Wv, const float* __restrict__ Wo,
           unsigned short* __restrict__ whi, unsigned short* __restrict__ wlo) {
    int gid = blockIdx.x, t = threadIdx.x;
    const float* src;
    int n, k;
    size_t oidx;
    if (gid < 1536) {
        int s = gid >> 8;
        int e = ((gid & 255) << 8) + t;
        n = e & 511; k = e >> 9;
        src = (s & 1) ? (gWr + (s >> 1) * 65536) : (gWl + (s >> 1) * 65536);
        oidx = (size_t)s * 65536 + n * 128 + k;
        float v = src[k * 512 + n];
        unsigned short h = bf16rn(v);
        whi[oidx] = h;
        wlo[oidx] = bf16rn(v - bf16f(h));
    } else {
        int g2 = gid - 1536;
        int s = g2 >> 6;
        int e = ((g2 & 63) << 8) + t;
        n = e & 127; k = e >> 7;
        src = (s == 0) ? Wq : (s == 1) ? Wk : (s == 2) ? Wv : Wo;
        oidx = 393216 + (size_t)s * 16384 + n * 128 + k;
        float v = src[k * 128 + n];
        unsigned short h = bf16rn(v);
        whi[oidx] = h;
        wlo[oidx] = bf16rn(v - bf16f(h));
    }
}

// ---------------- layer-0 projections (K=9) ----------------
__global__ __launch_bounds__(256)
void proj0(const float* __restrict__ x, const float* __restrict__ Wl,
           const float* __restrict__ Wr, const float* __restrict__ bl,
           const float* __restrict__ br, float* __restrict__ xl0,
           float* __restrict__ xr0) {
    int t = blockIdx.x * 256 + threadIdx.x;     // Nn*128 threads
    int n = t >> 7, j = t & 127;
    float xv[9];
#pragma unroll
    for (int k = 0; k < 9; ++k) xv[k] = x[n * 9 + k];
    float al = bl[j], ar = br[j];
#pragma unroll
    for (int k = 0; k < 9; ++k) {
        al = fmaf(xv[k], Wl[k * 128 + j], al);
        ar = fmaf(xv[k], Wr[k * 128 + j], ar);
    }
    xl0[t] = al;
    xr0[t] = ar;
}

// ---------------- bf16x3 MFMA GEMM, K=128, 128x128 tile ----------------
// C[M][NC] = epi( act(A[M][128]) @ W[128][NC] + bias )
// W pre-transposed bf16 hi/lo: wt[n][k].  A converted to hi/lo during staging.
// acc += Ah*Bh + Ah*Bl + Al*Bh   (lo*lo dropped: ~2^-16 relative)
// EPI 0: C = acc + bias     EPI 1 (NC==128): C = (res + acc + bias) * 0.5
template<bool RELU, int EPI>
__global__ __launch_bounds__(256, 2)
void gemm_mfma(const float* __restrict__ A, const unsigned short* __restrict__ wth,
               const unsigned short* __restrict__ wtl, const float* __restrict__ bias,
               const float* __restrict__ res, float* __restrict__ C, int NC) {
    // LDS: Ah/Al/Bh/Bl, each bf16[128 rows][64 k], XOR-swizzled, 16 KB each
    __shared__ __align__(16) char smem[65536];
    constexpr int AH = 0, AL = 16384, BH = 32768, BL = 49152;

    const int t = threadIdx.x;
    const int r0 = blockIdx.y * 128, c0 = blockIdx.x * 128;
    const int wave = t >> 6, lane = t & 63;
    const int wm = wave >> 1, wn = wave & 1;      // 2x2 wave grid, 64x64 each
    const int lr = lane & 15, lg = lane >> 4;

    f32x4 acc[4][4] = {};

    // per-frag LDS row bases
    int rowA[4], rowB[4];
#pragma unroll
    for (int i = 0; i < 4; ++i) {
        rowA[i] = wm * 64 + i * 16 + lr;
        rowB[i] = wn * 64 + i * 16 + lr;
    }

    for (int kc = 0; kc < 2; ++kc) {
        // ---- stage A (128 rows x 64 k fp32 -> hi/lo bf16, swizzled) ----
#pragma unroll
        for (int i = 0; i < 8; ++i) {
            int f = t + i * 256;               // 2048 float4
            int row = f >> 4;
            int c4  = (f & 15) << 2;           // k offset (floats)
            float4 v = *reinterpret_cast<const float4*>(
                &A[(size_t)(r0 + row) * 128 + kc * 64 + c4]);
            if (RELU) {
                v.x = fmaxf(v.x, 0.f); v.y = fmaxf(v.y, 0.f);
                v.z = fmaxf(v.z, 0.f); v.w = fmaxf(v.w, 0.f);
            }
            unsigned short h0 = bf16rn(v.x), h1 = bf16rn(v.y),
                           h2 = bf16rn(v.z), h3 = bf16rn(v.w);
            u16x4 hp = {h0, h1, h2, h3};
            u16x4 lp = {bf16rn(v.x - bf16f(h0)), bf16rn(v.y - bf16f(h1)),
                        bf16rn(v.z - bf16f(h2)), bf16rn(v.w - bf16f(h3))};
            int off = row * 128 + ((c4 * 2) ^ ((row & 7) << 4));
            *reinterpret_cast<u16x4*>(smem + AH + off) = hp;
            *reinterpret_cast<u16x4*>(smem + AL + off) = lp;
        }
        // ---- stage B (128 n-rows x 64 k bf16 from pre-transposed) ----
#pragma unroll
        for (int i = 0; i < 4; ++i) {
            int f = t + i * 256;               // 1024 16B chunks
            int row = f >> 3;
            int c8  = (f & 7) << 3;            // k offset (bf16)
            size_t gsrc = (size_t)(c0 + row) * 128 + kc * 64 + c8;
            s16x8 hv = *reinterpret_cast<const s16x8*>(&wth[gsrc]);
            s16x8 lv = *reinterpret_cast<const s16x8*>(&wtl[gsrc]);
            int off = row * 128 + ((c8 * 2) ^ ((row & 7) << 4));
            *reinterpret_cast<s16x8*>(smem + BH + off) = hv;
            *reinterpret_cast<s16x8*>(smem + BL + off) = lv;
        }
        __syncthreads();

        // ---- MFMA: 2 k-steps of 32 per chunk ----
#pragma unroll
        for (int ks = 0; ks < 2; ++ks) {
            const int kb = ks * 64 + lg * 16;  // byte offset of lane's 8 bf16
            s16x8 ah[4], al4[4];
#pragma unroll
            for (int mi = 0; mi < 4; ++mi) {
                int off = rowA[mi] * 128 + (kb ^ ((rowA[mi] & 7) << 4));
                ah[mi]  = *reinterpret_cast<const s16x8*>(smem + AH + off);
                al4[mi] = *reinterpret_cast<const s16x8*>(smem + AL + off);
            }
#pragma unroll
            for (int ni = 0; ni < 4; ++ni) {
                int off = rowB[ni] * 128 + (kb ^ ((rowB[ni] & 7) << 4));
                s16x8 bh = *reinterpret_cast<const s16x8*>(smem + BH + off);
                s16x8 bl = *reinterpret_cast<const s16x8*>(smem + BL + off);
#pragma unroll
                for (int mi = 0; mi < 4; ++mi) {
                    acc[mi][ni] = __builtin_amdgcn_mfma_f32_16x16x32_bf16(
                        ah[mi], bh, acc[mi][ni], 0, 0, 0);
                    acc[mi][ni] = __builtin_amdgcn_mfma_f32_16x16x32_bf16(
                        ah[mi], bl, acc[mi][ni], 0, 0, 0);
                    acc[mi][ni] = __builtin_amdgcn_mfma_f32_16x16x32_bf16(
                        al4[mi], bh, acc[mi][ni], 0, 0, 0);
                }
            }
        }
        __syncthreads();
    }

    // ---- epilogue: C[row=(lg*4+j)][col=lr] per 16x16 frag ----
#pragma unroll
    for (int ni = 0; ni < 4; ++ni) {
        int c = c0 + wn * 64 + ni * 16 + lr;
        float bs = bias[c];
#pragma unroll
        for (int mi = 0; mi < 4; ++mi) {
#pragma unroll
            for (int j = 0; j < 4; ++j) {
                int r = r0 + wm * 64 + mi * 16 + lg * 4 + j;
                float ov = acc[mi][ni][j] + bs;
                if (EPI == 1) ov = (ov + res[(size_t)r * 128 + c]) * 0.5f;
                C[(size_t)r * NC + c] = ov;
            }
        }
    }
}

// ---------------- GATv2 edge kernel: alpha -> dense P, then P@X ----------------
template<int HEADS, int EPI>
__global__ __launch_bounds__(512, 4)
void gat_edge(const float* __restrict__ xl, const float* __restrict__ xr,
              const int* __restrict__ ei, const float* __restrict__ ea,
              const float* __restrict__ We, const float* __restrict__ att,
              const float* __restrict__ bias, const float* __restrict__ hres,
              float* __restrict__ hout, int g0) {
    constexpr int WROW = HEADS * 128;
    constexpr int PST  = 68;
    __shared__ __align__(16) float xls[64 * 128];
    __shared__ __align__(16) float xrp[64 * 128];   // xr tile; aliased by P after logits
    __shared__ float eas[EPG * 4];
    __shared__ float logit[EPG];
    __shared__ int   se[EPG], de[EPG];
    __shared__ unsigned nmax[64];
    __shared__ float nden[64];

    const int g = g0 + blockIdx.x;
    const int t = threadIdx.x, lane = t & 63, wave = t >> 6;
    const int rg = (t >> 5) << 2;
    const int cg = (t & 31) << 2;

    if (t < EPG) {
        se[t] = ei[g * EPG + t] - g * 64;
        de[t] = ei[Ne + g * EPG + t] - g * 64;
        eas[t * 4 + 0] = ea[(size_t)(g * EPG + t) * 3 + 0];
        eas[t * 4 + 1] = ea[(size_t)(g * EPG + t) * 3 + 1];
        eas[t * 4 + 2] = ea[(size_t)(g * EPG + t) * 3 + 2];
    }

    float acc[4][4] = {};

    for (int hh = 0; hh < HEADS; ++hh) {
        __syncthreads();
#pragma unroll
        for (int i = 0; i < 4; ++i) {
            int f  = t + i * 512;
            int r  = f >> 5;
            int c4 = (f & 31) << 2;
            size_t nl = (size_t)((g - g0) * 64 + r);
            *reinterpret_cast<float4*>(&xls[r * 128 + c4]) =
                *reinterpret_cast<const float4*>(&xl[nl * WROW + hh * 128 + c4]);
            *reinterpret_cast<float4*>(&xrp[r * 128 + c4]) =
                *reinterpret_cast<const float4*>(&xr[nl * WROW + hh * 128 + c4]);
        }
        if (t < 64) { nmax[t] = 0u; nden[t] = 0.f; }
        __syncthreads();

        const float a1 = att[hh * 128 + lane];
        const float a2 = att[hh * 128 + 64 + lane];
        float we1[3], we2[3];
#pragma unroll
        for (int k = 0; k < 3; ++k) {
            we1[k] = We[k * WROW + hh * 128 + lane];
            we2[k] = We[k * WROW + hh * 128 + 64 + lane];
        }

        for (int e = wave; e < EPG; e += 8) {
            int s_ = se[e], d_ = de[e];
            float e0 = eas[e * 4 + 0], e1 = eas[e * 4 + 1], e2 = eas[e * 4 + 2];
            float m1 = xls[s_ * 128 + lane] + xrp[d_ * 128 + lane]
                       + e0 * we1[0] + e1 * we1[1] + e2 * we1[2];
            float m2 = xls[s_ * 128 + 64 + lane] + xrp[d_ * 128 + 64 + lane]
                       + e0 * we2[0] + e1 * we2[1] + e2 * we2[2];
            m1 = m1 > 0.f ? m1 : NEG * m1;
            m2 = m2 > 0.f ? m2 : NEG * m2;
            float r = fmaf(m1, a1, m2 * a2);
#pragma unroll
            for (int o = 32; o; o >>= 1) r += __shfl_xor(r, o, 64);
            if (lane == 0) logit[e] = r;
        }
        __syncthreads();

        float* P = xrp;
        for (int i = t; i < 64 * PST; i += 512) P[i] = 0.f;
        if (t < EPG) atomicMax(&nmax[de[t]], fenc(logit[t]));
        __syncthreads();
        float ex = 0.f;
        if (t < EPG) {
            ex = __expf(logit[t] - fdec(nmax[de[t]]));
            atomicAdd(&nden[de[t]], ex);
        }
        __syncthreads();
        if (t < EPG) atomicAdd(&P[se[t] * PST + de[t]], ex / nden[de[t]]);
        __syncthreads();

#pragma unroll 4
        for (int k = 0; k < 64; ++k) {
            float4 pv = *reinterpret_cast<const float4*>(&P[k * PST + rg]);
            float4 xv = *reinterpret_cast<const float4*>(&xls[k * 128 + cg]);
            acc[0][0] = fmaf(pv.x, xv.x, acc[0][0]);
            acc[0][1] = fmaf(pv.x, xv.y, acc[0][1]);
            acc[0][2] = fmaf(pv.x, xv.z, acc[0][2]);
            acc[0][3] = fmaf(pv.x, xv.w, acc[0][3]);
            acc[1][0] = fmaf(pv.y, xv.x, acc[1][0]);
            acc[1][1] = fmaf(pv.y, xv.y, acc[1][1]);
            acc[1][2] = fmaf(pv.y, xv.z, acc[1][2]);
            acc[1][3] = fmaf(pv.y, xv.w, acc[1][3]);
            acc[2][0] = fmaf(pv.z, xv.x, acc[2][0]);
            acc[2][1] = fmaf(pv.z, xv.y, acc[2][1]);
            acc[2][2] = fmaf(pv.z, xv.z, acc[2][2]);
            acc[2][3] = fmaf(pv.z, xv.w, acc[2][3]);
            acc[3][0] = fmaf(pv.w, xv.x, acc[3][0]);
            acc[3][1] = fmaf(pv.w, xv.y, acc[3][1]);
            acc[3][2] = fmaf(pv.w, xv.z, acc[3][2]);
            acc[3][3] = fmaf(pv.w, xv.w, acc[3][3]);
        }
    }

    constexpr float inv = 1.0f / (float)HEADS;
#pragma unroll
    for (int i = 0; i < 4; ++i) {
        int r = rg + i;
        size_t gi = (size_t)(g * 64 + r) * 128 + cg;
        float4 v;
        v.x = acc[i][0] * inv + bias[cg + 0];
        v.y = acc[i][1] * inv + bias[cg + 1];
        v.z = acc[i][2] * inv + bias[cg + 2];
        v.w = acc[i][3] * inv + bias[cg + 3];
        if (EPI == 1) {
            const float4 rr = *reinterpret_cast<const float4*>(&hres[gi]);
            v.x = (v.x + rr.x) * 0.5f; v.y = (v.y + rr.y) * 0.5f;
            v.z = (v.z + rr.z) * 0.5f; v.w = (v.w + rr.w) * 0.5f;
        }
        *reinterpret_cast<float4*>(&hout[gi]) = v;
    }
}

// ---------------- dense attention v2: one block per (graph, head) ----------------
__global__ __launch_bounds__(256, 3)
void attn_k(const float* __restrict__ q, const float* __restrict__ k,
            const float* __restrict__ v, float* __restrict__ o) {
    __shared__ __align__(16) float qT[32 * 68];    // [k][row]
    __shared__ __align__(16) float kT[32 * 68];    // [k][col]
    __shared__ __align__(16) float vs[64 * 36];    // [k][d]
    __shared__ __align__(16) float St[64 * 68];    // [col][row] scores -> exp
    __shared__ float rden[64];

    const int g = blockIdx.x >> 2, hh = blockIdx.x & 3;
    const int t = threadIdx.x;

    // stage q,k (transposed) and v
#pragma unroll
    for (int i = 0; i < 2; ++i) {
        int f = t + i * 256;                   // 512 float4
        int row = f >> 3;
        int c4  = (f & 7) << 2;
        size_t gi = (size_t)(g * 64 + row) * 128 + hh * 32 + c4;
        float4 qv = *reinterpret_cast<const float4*>(&q[gi]);
        float4 kv = *reinterpret_cast<const float4*>(&k[gi]);
        float4 vv = *reinterpret_cast<const float4*>(&v[gi]);
        qT[(c4 + 0) * 68 + row] = qv.x; qT[(c4 + 1) * 68 + row] = qv.y;
        qT[(c4 + 2) * 68 + row] = qv.z; qT[(c4 + 3) * 68 + row] = qv.w;
        kT[(c4 + 0) * 68 + row] = kv.x; kT[(c4 + 1) * 68 + row] = kv.y;
        kT[(c4 + 2) * 68 + row] = kv.z; kT[(c4 + 3) * 68 + row] = kv.w;
        *reinterpret_cast<float4*>(&vs[row * 36 + c4]) = vv;
    }
    __syncthreads();

    // scores: thread tile 4 rows (rg) x 4 cols (cg); k inner
    {
        const int rg = (t & 15) << 2, cg = (t >> 4) << 2;
        float acc[4][4] = {};
#pragma unroll 8
        for (int kk = 0; kk < 32; ++kk) {
            float4 qv = *reinterpret_cast<const float4*>(&qT[kk * 68 + rg]);
            float4 kv = *reinterpret_cast<const float4*>(&kT[kk * 68 + cg]);
            acc[0][0] = fmaf(qv.x, kv.x, acc[0][0]);
            acc[0][1] = fmaf(qv.x, kv.y, acc[0][1]);
            acc[0][2] = fmaf(qv.x, kv.z, acc[0][2]);
            acc[0][3] = fmaf(qv.x, kv.w, acc[0][3]);
            acc[1][0] = fmaf(qv.y, kv.x, acc[1][0]);
            acc[1][1] = fmaf(qv.y, kv.y, acc[1][1]);
            acc[1][2] = fmaf(qv.y, kv.z, acc[1][2]);
            acc[1][3] = fmaf(qv.y, kv.w, acc[1][3]);
            acc[2][0] = fmaf(qv.z, kv.x, acc[2][0]);
            acc[2][1] = fmaf(qv.z, kv.y, acc[2][1]);
            acc[2][2] = fmaf(qv.z, kv.z, acc[2][2]);
            acc[2][3] = fmaf(qv.z, kv.w, acc[2][3]);
            acc[3][0] = fmaf(qv.w, kv.x, acc[3][0]);
            acc[3][1] = fmaf(qv.w, kv.y, acc[3][1]);
            acc[3][2] = fmaf(qv.w, kv.z, acc[3][2]);
            acc[3][3] = fmaf(qv.w, kv.w, acc[3][3]);
        }
        constexpr float sc = 0.17677669529663687f;   // 1/sqrt(32)
#pragma unroll
        for (int j = 0; j < 4; ++j) {
            float4 sv;
            sv.x = acc[0][j] * sc; sv.y = acc[1][j] * sc;
            sv.z = acc[2][j] * sc; sv.w = acc[3][j] * sc;
            *reinterpret_cast<float4*>(&St[(cg + j) * 68 + rg]) = sv;
        }
    }
    __syncthreads();

    // softmax over cols (St is [col][row]); denom folded into epilogue
    {
        const int r = t >> 2, q4 = t & 3;
        float mx = -3.4e38f;
#pragma unroll
        for (int i = 0; i < 16; ++i)
            mx = fmaxf(mx, St[(q4 * 16 + i) * 68 + r]);
        mx = fmaxf(mx, __shfl_xor(mx, 1, 64));
        mx = fmaxf(mx, __shfl_xor(mx, 2, 64));
        float sm = 0.f;
#pragma unroll
        for (int i = 0; i < 16; ++i) {
            int idx = (q4 * 16 + i) * 68 + r;
            float e = __expf(St[idx] - mx);
            St[idx] = e;
            sm += e;
        }
        sm += __shfl_xor(sm, 1, 64);
        sm += __shfl_xor(sm, 2, 64);
        if (q4 == 0) rden[r] = 1.f / sm;
    }
    __syncthreads();

    // PV: thread tile 4 rows x 2 d-cols; k inner
    {
        const int rg = (t & 15) << 2, dg = (t >> 4) << 1;
        float a0 = 0.f, a1 = 0.f, a2 = 0.f, a3 = 0.f;
        float b0 = 0.f, b1 = 0.f, b2 = 0.f, b3 = 0.f;
#pragma unroll 8
        for (int kk = 0; kk < 64; ++kk) {
            float4 pv = *reinterpret_cast<const float4*>(&St[kk * 68 + rg]);
            float2 vv = *reinterpret_cast<const float2*>(&vs[kk * 36 + dg]);
            a0 = fmaf(pv.x, vv.x, a0); b0 = fmaf(pv.x, vv.y, b0);
            a1 = fmaf(pv.y, vv.x, a1); b1 = fmaf(pv.y, vv.y, b1);
            a2 = fmaf(pv.z, vv.x, a2); b2 = fmaf(pv.z, vv.y, b2);
            a3 = fmaf(pv.w, vv.x, a3); b3 = fmaf(pv.w, vv.y, b3);
        }
        float4 rd = *reinterpret_cast<const float4*>(&rden[rg]);
        float2 o0 = {a0 * rd.x, b0 * rd.x};
        float2 o1 = {a1 * rd.y, b1 * rd.y};
        float2 o2 = {a2 * rd.z, b2 * rd.z};
        float2 o3 = {a3 * rd.w, b3 * rd.w};
        size_t gb = (size_t)(g * 64 + rg) * 128 + hh * 32 + dg;
        *reinterpret_cast<float2*>(&o[gb])           = o0;
        *reinterpret_cast<float2*>(&o[gb + 128])     = o1;
        *reinterpret_cast<float2*>(&o[gb + 256])     = o2;
        *reinterpret_cast<float2*>(&o[gb + 384])     = o3;
    }
}

// ---------------- launch ----------------
extern "C" void kernel_launch(void* const* d_in, const int* in_sizes, int n_in,
                              void* d_out, int out_size, void* d_ws, size_t ws_size,
                              hipStream_t stream) {
    const float* x     = (const float*)d_in[0];
    const int*   ei    = (const int*)d_in[1];
    const float* ea    = (const float*)d_in[2];
    const float* g0Wl  = (const float*)d_in[4];
    const float* g0Wr  = (const float*)d_in[5];
    const float* g0bl  = (const float*)d_in[6];
    const float* g0br  = (const float*)d_in[7];
    const float* g0We  = (const float*)d_in[8];
    const float* g0att = (const float*)d_in[9];
    const float* g0bias= (const float*)d_in[10];
    const float* gWl   = (const float*)d_in[11];
    const float* gWr   = (const float*)d_in[12];
    const float* gbl   = (const float*)d_in[13];
    const float* gbr   = (const float*)d_in[14];
    const float* gWe   = (const float*)d_in[15];
    const float* gatt  = (const float*)d_in[16];
    const float* gbias = (const float*)d_in[17];
    const float* Wq    = (const float*)d_in[18];
    const float* Wk    = (const float*)d_in[19];
    const float* Wv    = (const float*)d_in[20];
    const float* bq    = (const float*)d_in[21];
    const float* bk    = (const float*)d_in[22];
    const float* bv    = (const float*)d_in[23];
    const float* Wo    = (const float*)d_in[24];
    const float* bo    = (const float*)d_in[25];
    float* out = (float*)d_out;
    float* ws  = (float*)d_ws;

    float* h   = ws;                                   // Nn*128
    float* xlb = ws + (size_t)Nn * 128;                // CHUNK_N*512
    float* xrb = xlb + (size_t)CHUNK_N * 512;          // CHUNK_N*512
    float* qb = xlb;
    float* kb = xlb + (size_t)Nn * 128;
    float* vb = xrb;
    float* ob = xrb + (size_t)Nn * 128;
    // bf16 hi/lo weight store after the big buffers (~1.8 MB)
    unsigned short* whi = (unsigned short*)(xrb + (size_t)CHUNK_N * 512);
    unsigned short* wlo = whi + 458752;

    wprep<<<1792, 256, 0, stream>>>(gWl, gWr, Wq, Wk, Wv, Wo, whi, wlo);

    // ---- layer 0 (heads=1, concat) ----
    proj0<<<Nn * 128 / 256, 256, 0, stream>>>(x, g0Wl, g0Wr, g0bl, g0br, xlb, xrb);
    gat_edge<1, 0><<<Bg, 512, 0, stream>>>(xlb, xrb, ei, ea, g0We, g0att,
                                           g0bias, nullptr, h, 0);

    // ---- layers 1..3 (heads=4, mean, residual) ----
    for (int i = 0; i < 3; ++i) {
        for (int c = 0; c < 2; ++c) {
            const float* Ain = h + (size_t)c * CHUNK_N * 128;
            dim3 grid(512 / 128, CHUNK_N / 128);
            gemm_mfma<true, 0><<<grid, 256, 0, stream>>>(
                Ain, whi + (size_t)(2 * i) * 65536, wlo + (size_t)(2 * i) * 65536,
                gbl + i * 512, nullptr, xlb, 512);
            gemm_mfma<true, 0><<<grid, 256, 0, stream>>>(
                Ain, whi + (size_t)(2 * i + 1) * 65536, wlo + (size_t)(2 * i + 1) * 65536,
                gbr + i * 512, nullptr, xrb, 512);
            gat_edge<4, 1><<<CHUNK_G, 512, 0, stream>>>(
                xlb, xrb, ei, ea, gWe + (size_t)i * 3 * 512,
                gatt + (size_t)i * 4 * 128, gbias + i * 128, h, h, c * CHUNK_G);
        }
    }

    // ---- dense attention over graphs ----
    {
        dim3 grid(1, Nn / 128);
        gemm_mfma<false, 0><<<grid, 256, 0, stream>>>(h, whi + 393216, wlo + 393216,
                                                      bq, nullptr, qb, 128);
        gemm_mfma<false, 0><<<grid, 256, 0, stream>>>(h, whi + 409600, wlo + 409600,
                                                      bk, nullptr, kb, 128);
        gemm_mfma<false, 0><<<grid, 256, 0, stream>>>(h, whi + 425984, wlo + 425984,
                                                      bv, nullptr, vb, 128);
        attn_k<<<Bg * NH, 256, 0, stream>>>(qb, kb, vb, ob);
        gemm_mfma<false, 1><<<grid, 256, 0, stream>>>(ob, whi + 442368, wlo + 442368,
                                                      bo, h, out, 128);
    }
}

// Round 6
// 1049.245 us; speedup vs baseline: 3.9335x; 1.1602x over previous
//
#include <hip/hip_runtime.h>

// Problem constants
constexpr int Bg  = 1024;          // graphs
constexpr int Sg  = 64;            // nodes per graph
constexpr int EPG = 256;           // edges per graph
constexpr int Nn  = Bg * Sg;       // 65536 nodes
constexpr int Ne  = Bg * EPG;      // 262144 edges
constexpr int NH  = 4;             // attention heads
constexpr float NEG = 0.2f;

constexpr int CHUNK_G = 512;               // graphs per GAT-layer chunk
constexpr int CHUNK_N = CHUNK_G * Sg;      // 32768 nodes

typedef float  f32x4  __attribute__((ext_vector_type(4)));
typedef short  s16x8  __attribute__((ext_vector_type(8)));
typedef unsigned short u16x4 __attribute__((ext_vector_type(4)));

static __device__ __forceinline__ unsigned fenc(float f) {
    unsigned u = __float_as_uint(f);
    return (u & 0x80000000u) ? ~u : (u | 0x80000000u);
}
static __device__ __forceinline__ float fdec(unsigned k) {
    unsigned u = (k & 0x80000000u) ? (k ^ 0x80000000u) : ~k;
    return __uint_as_float(u);
}
static __device__ __forceinline__ unsigned short bf16rn(float x) {
    unsigned u = __float_as_uint(x);
    u += 0x7FFFu + ((u >> 16) & 1u);
    return (unsigned short)(u >> 16);
}
static __device__ __forceinline__ float bf16f(unsigned short h) {
    return __uint_as_float((unsigned)h << 16);
}
// pack fp32 -> (bf16 hi | bf16 lo) in one u32; hi+lo reconstructs x to ~2^-16 rel
static __device__ __forceinline__ unsigned pack32(float x) {
    unsigned u  = __float_as_uint(x);
    unsigned hb = u & 0xffff0000u;
    float lof   = x - __uint_as_float(hb);
    return hb | (__float_as_uint(lof) >> 16);
}
static __device__ __forceinline__ float up_hi(unsigned u) {
    return __uint_as_float(u & 0xffff0000u);
}
static __device__ __forceinline__ float up_lo(unsigned u) {
    return __uint_as_float(u << 16);
}
// wave64 sum via DPP: row_shr 1,2,4,8 then row_bcast 15,31; total lands in lane 63
#define DPP_ADD(x, ctrl) \
    ((x) + __int_as_float(__builtin_amdgcn_update_dpp( \
        0, __float_as_int(x), (ctrl), 0xF, 0xF, true)))

// ---------------- weight prep: transpose + hi/lo bf16 split ----------------
__global__ __launch_bounds__(256)
void wprep(const float* __restrict__ gWl, const float* __restrict__ gWr,
           const float* __restrict__ Wq, const float* __restrict__ Wk,
           const float* __restrict__ Wv, const float* __restrict__ Wo,
           unsigned short* __restrict__ whi, unsigned short* __restrict__ wlo) {
    int gid = blockIdx.x, t = threadIdx.x;
    const float* src;
    int n, k;
    size_t oidx;
    if (gid < 1536) {
        int s = gid >> 8;
        int e = ((gid & 255) << 8) + t;
        n = e & 511; k = e >> 9;
        src = (s & 1) ? (gWr + (s >> 1) * 65536) : (gWl + (s >> 1) * 65536);
        oidx = (size_t)s * 65536 + n * 128 + k;
        float v = src[k * 512 + n];
        unsigned short h = bf16rn(v);
        whi[oidx] = h;
        wlo[oidx] = bf16rn(v - bf16f(h));
    } else {
        int g2 = gid - 1536;
        int s = g2 >> 6;
        int e = ((g2 & 63) << 8) + t;
        n = e & 127; k = e >> 7;
        src = (s == 0) ? Wq : (s == 1) ? Wk : (s == 2) ? Wv : Wo;
        oidx = 393216 + (size_t)s * 16384 + n * 128 + k;
        float v = src[k * 128 + n];
        unsigned short h = bf16rn(v);
        whi[oidx] = h;
        wlo[oidx] = bf16rn(v - bf16f(h));
    }
}

// ---------------- layer-0 projections (K=9) ----------------
__global__ __launch_bounds__(256)
void proj0(const float* __restrict__ x, const float* __restrict__ Wl,
           const float* __restrict__ Wr, const float* __restrict__ bl,
           const float* __restrict__ br, float* __restrict__ xl0,
           float* __restrict__ xr0) {
    int t = blockIdx.x * 256 + threadIdx.x;     // Nn*128 threads
    int n = t >> 7, j = t & 127;
    float xv[9];
#pragma unroll
    for (int k = 0; k < 9; ++k) xv[k] = x[n * 9 + k];
    float al = bl[j], ar = br[j];
#pragma unroll
    for (int k = 0; k < 9; ++k) {
        al = fmaf(xv[k], Wl[k * 128 + j], al);
        ar = fmaf(xv[k], Wr[k * 128 + j], ar);
    }
    xl0[t] = al;
    xr0[t] = ar;
}

// ---------------- bf16x3 MFMA GEMM, K=128, 128x128 tile ----------------
template<bool RELU, int EPI>
__global__ __launch_bounds__(256, 2)
void gemm_mfma(const float* __restrict__ A, const unsigned short* __restrict__ wth,
               const unsigned short* __restrict__ wtl, const float* __restrict__ bias,
               const float* __restrict__ res, float* __restrict__ C, int NC) {
    __shared__ __align__(16) char smem[65536];
    constexpr int AH = 0, AL = 16384, BH = 32768, BL = 49152;

    const int t = threadIdx.x;
    const int r0 = blockIdx.y * 128, c0 = blockIdx.x * 128;
    const int wave = t >> 6, lane = t & 63;
    const int wm = wave >> 1, wn = wave & 1;
    const int lr = lane & 15, lg = lane >> 4;

    f32x4 acc[4][4] = {};

    int rowA[4], rowB[4];
#pragma unroll
    for (int i = 0; i < 4; ++i) {
        rowA[i] = wm * 64 + i * 16 + lr;
        rowB[i] = wn * 64 + i * 16 + lr;
    }

    for (int kc = 0; kc < 2; ++kc) {
#pragma unroll
        for (int i = 0; i < 8; ++i) {
            int f = t + i * 256;
            int row = f >> 4;
            int c4  = (f & 15) << 2;
            float4 v = *reinterpret_cast<const float4*>(
                &A[(size_t)(r0 + row) * 128 + kc * 64 + c4]);
            if (RELU) {
                v.x = fmaxf(v.x, 0.f); v.y = fmaxf(v.y, 0.f);
                v.z = fmaxf(v.z, 0.f); v.w = fmaxf(v.w, 0.f);
            }
            unsigned short h0 = bf16rn(v.x), h1 = bf16rn(v.y),
                           h2 = bf16rn(v.z), h3 = bf16rn(v.w);
            u16x4 hp = {h0, h1, h2, h3};
            u16x4 lp = {bf16rn(v.x - bf16f(h0)), bf16rn(v.y - bf16f(h1)),
                        bf16rn(v.z - bf16f(h2)), bf16rn(v.w - bf16f(h3))};
            int off = row * 128 + ((c4 * 2) ^ ((row & 7) << 4));
            *reinterpret_cast<u16x4*>(smem + AH + off) = hp;
            *reinterpret_cast<u16x4*>(smem + AL + off) = lp;
        }
#pragma unroll
        for (int i = 0; i < 4; ++i) {
            int f = t + i * 256;
            int row = f >> 3;
            int c8  = (f & 7) << 3;
            size_t gsrc = (size_t)(c0 + row) * 128 + kc * 64 + c8;
            s16x8 hv = *reinterpret_cast<const s16x8*>(&wth[gsrc]);
            s16x8 lv = *reinterpret_cast<const s16x8*>(&wtl[gsrc]);
            int off = row * 128 + ((c8 * 2) ^ ((row & 7) << 4));
            *reinterpret_cast<s16x8*>(smem + BH + off) = hv;
            *reinterpret_cast<s16x8*>(smem + BL + off) = lv;
        }
        __syncthreads();

#pragma unroll
        for (int ks = 0; ks < 2; ++ks) {
            const int kb = ks * 64 + lg * 16;
            s16x8 ah[4], al4[4];
#pragma unroll
            for (int mi = 0; mi < 4; ++mi) {
                int off = rowA[mi] * 128 + (kb ^ ((rowA[mi] & 7) << 4));
                ah[mi]  = *reinterpret_cast<const s16x8*>(smem + AH + off);
                al4[mi] = *reinterpret_cast<const s16x8*>(smem + AL + off);
            }
#pragma unroll
            for (int ni = 0; ni < 4; ++ni) {
                int off = rowB[ni] * 128 + (kb ^ ((rowB[ni] & 7) << 4));
                s16x8 bh = *reinterpret_cast<const s16x8*>(smem + BH + off);
                s16x8 bl = *reinterpret_cast<const s16x8*>(smem + BL + off);
#pragma unroll
                for (int mi = 0; mi < 4; ++mi) {
                    acc[mi][ni] = __builtin_amdgcn_mfma_f32_16x16x32_bf16(
                        ah[mi], bh, acc[mi][ni], 0, 0, 0);
                    acc[mi][ni] = __builtin_amdgcn_mfma_f32_16x16x32_bf16(
                        ah[mi], bl, acc[mi][ni], 0, 0, 0);
                    acc[mi][ni] = __builtin_amdgcn_mfma_f32_16x16x32_bf16(
                        al4[mi], bh, acc[mi][ni], 0, 0, 0);
                }
            }
        }
        __syncthreads();
    }

#pragma unroll
    for (int ni = 0; ni < 4; ++ni) {
        int c = c0 + wn * 64 + ni * 16 + lr;
        float bs = bias[c];
#pragma unroll
        for (int mi = 0; mi < 4; ++mi) {
#pragma unroll
            for (int j = 0; j < 4; ++j) {
                int r = r0 + wm * 64 + mi * 16 + lg * 4 + j;
                float ov = acc[mi][ni][j] + bs;
                if (EPI == 1) ov = (ov + res[(size_t)r * 128 + c]) * 0.5f;
                C[(size_t)r * NC + c] = ov;
            }
        }
    }
}

// ---------------- GATv2 edge kernel v3 ----------------
// Per head: stage packed-bf16 x-tiles -> b64-gather + DPP-reduce logits ->
// LDS segment softmax -> P[dst][src] fp32 (aliased over XR) -> MFMA P@X
// with bf16x3 (A from P rows, B gathered from packed XL), acc in regs.
template<int HEADS, int EPI>
__global__ __launch_bounds__(512, 4)
void gat_edge(const float* __restrict__ xl, const float* __restrict__ xr,
              const int* __restrict__ ei, const float* __restrict__ ea,
              const float* __restrict__ We, const float* __restrict__ att,
              const float* __restrict__ bias, const float* __restrict__ hres,
              float* __restrict__ hout, int g0) {
    constexpr int WROW = HEADS * 128;
    __shared__ __align__(16) unsigned xli[64 * 128];   // packed (hi|lo) xl tile
    __shared__ __align__(16) unsigned xri[64 * 128];   // packed xr; aliased by P32[64][68]
    __shared__ float eas[EPG * 4];
    __shared__ float logit[EPG];
    __shared__ int   se[EPG], de[EPG];
    __shared__ unsigned nmax[64];
    __shared__ float nden[64];

    const int g = g0 + blockIdx.x;
    const int t = threadIdx.x, lane = t & 63, wave = t >> 6;   // 8 waves
    const int lr = lane & 15, lg = lane >> 4;
    const int wm = wave >> 2, wn = wave & 3;    // 2 (dst-half) x 4 (dim-quarter)

    if (t < EPG) {
        se[t] = ei[g * EPG + t] - g * 64;
        de[t] = ei[Ne + g * EPG + t] - g * 64;
        eas[t * 4 + 0] = ea[(size_t)(g * EPG + t) * 3 + 0];
        eas[t * 4 + 1] = ea[(size_t)(g * EPG + t) * 3 + 1];
        eas[t * 4 + 2] = ea[(size_t)(g * EPG + t) * 3 + 2];
    }

    f32x4 acc[2][2] = {};
    float* P32 = reinterpret_cast<float*>(xri);

    for (int hh = 0; hh < HEADS; ++hh) {
        __syncthreads();   // prev head's MFMA done with xli / P32
        // ---- stage packed tiles ----
#pragma unroll
        for (int i = 0; i < 4; ++i) {
            int f  = t + i * 512;                 // 2048 float4 groups
            int r  = f >> 5;
            int c4 = (f & 31) << 2;
            size_t nl = (size_t)((g - g0) * 64 + r);
            float4 vl = *reinterpret_cast<const float4*>(&xl[nl * WROW + hh * 128 + c4]);
            float4 vr = *reinterpret_cast<const float4*>(&xr[nl * WROW + hh * 128 + c4]);
            uint4 pl = {pack32(vl.x), pack32(vl.y), pack32(vl.z), pack32(vl.w)};
            uint4 pr = {pack32(vr.x), pack32(vr.y), pack32(vr.z), pack32(vr.w)};
            *reinterpret_cast<uint4*>(&xli[r * 128 + c4]) = pl;
            *reinterpret_cast<uint4*>(&xri[r * 128 + c4]) = pr;
        }
        if (t < 64) { nmax[t] = 0u; nden[t] = 0.f; }
        __syncthreads();

        // per-lane constants: this lane owns dims 2*lane, 2*lane+1
        const float a1 = att[hh * 128 + 2 * lane];
        const float a2 = att[hh * 128 + 2 * lane + 1];
        float we1[3], we2[3];
#pragma unroll
        for (int k = 0; k < 3; ++k) {
            we1[k] = We[k * WROW + hh * 128 + 2 * lane];
            we2[k] = We[k * WROW + hh * 128 + 2 * lane + 1];
        }

        // ---- logits: b64 gather + DPP wave-reduce (no LDS shuffles) ----
        for (int e = wave; e < EPG; e += 8) {
            int s_ = se[e], d_ = de[e];
            float4 ev = *reinterpret_cast<const float4*>(&eas[e * 4]);
            uint2 ul = *reinterpret_cast<const uint2*>(&xli[s_ * 128 + 2 * lane]);
            uint2 ur = *reinterpret_cast<const uint2*>(&xri[d_ * 128 + 2 * lane]);
            float m1 = up_hi(ul.x) + up_lo(ul.x) + up_hi(ur.x) + up_lo(ur.x)
                       + ev.x * we1[0] + ev.y * we1[1] + ev.z * we1[2];
            float m2 = up_hi(ul.y) + up_lo(ul.y) + up_hi(ur.y) + up_lo(ur.y)
                       + ev.x * we2[0] + ev.y * we2[1] + ev.z * we2[2];
            m1 = m1 > 0.f ? m1 : NEG * m1;
            m2 = m2 > 0.f ? m2 : NEG * m2;
            float r = fmaf(m1, a1, m2 * a2);
            r = DPP_ADD(r, 0x111);   // row_shr:1
            r = DPP_ADD(r, 0x112);   // row_shr:2
            r = DPP_ADD(r, 0x114);   // row_shr:4
            r = DPP_ADD(r, 0x118);   // row_shr:8  -> lane15/31/47/63 hold row sums
            r = DPP_ADD(r, 0x142);   // row_bcast:15
            r = DPP_ADD(r, 0x143);   // row_bcast:31 -> lane63 = total
            if (lane == 63) logit[e] = r;
        }
        __syncthreads();

        // ---- segment softmax; xr tile dead -> P32[dst][src] stride 68 ----
        for (int i = t; i < 1088; i += 512)
            reinterpret_cast<float4*>(P32)[i] = float4{0.f, 0.f, 0.f, 0.f};
        if (t < EPG) atomicMax(&nmax[de[t]], fenc(logit[t]));
        __syncthreads();
        float ex = 0.f;
        if (t < EPG) {
            ex = __expf(logit[t] - fdec(nmax[de[t]]));
            atomicAdd(&nden[de[t]], ex);
        }
        __syncthreads();
        if (t < EPG) atomicAdd(&P32[de[t] * 68 + se[t]], ex / nden[de[t]]);
        __syncthreads();

        // ---- MFMA P@X: out[dst][dim] += P[dst][src] * X[src][dim] ----
#pragma unroll
        for (int ks = 0; ks < 2; ++ks) {
            // B-frags: gather X^T columns from packed xli (hi/lo free split)
            s16x8 bh[2], bl[2];
#pragma unroll
            for (int nt = 0; nt < 2; ++nt) {
                int n = wn * 32 + nt * 16 + lr;
                unsigned uu[8];
#pragma unroll
                for (int j = 0; j < 8; ++j)
                    uu[j] = xli[(ks * 32 + lg * 8 + j) * 128 + n];
#pragma unroll
                for (int j = 0; j < 8; ++j) {
                    bh[nt][j] = (short)(uu[j] >> 16);
                    bl[nt][j] = (short)(uu[j] & 0xffffu);
                }
            }
#pragma unroll
            for (int mi = 0; mi < 2; ++mi) {
                const float* pr = &P32[(wm * 32 + mi * 16 + lr) * 68 + ks * 32 + lg * 8];
                float4 p0 = *reinterpret_cast<const float4*>(pr);
                float4 p1 = *reinterpret_cast<const float4*>(pr + 4);
                float pv[8] = {p0.x, p0.y, p0.z, p0.w, p1.x, p1.y, p1.z, p1.w};
                s16x8 pah, pal;
#pragma unroll
                for (int j = 0; j < 8; ++j) {
                    unsigned u = __float_as_uint(pv[j]);
                    unsigned hb = u & 0xffff0000u;
                    pah[j] = (short)(u >> 16);
                    pal[j] = (short)(__float_as_uint(pv[j] - __uint_as_float(hb)) >> 16);
                }
#pragma unroll
                for (int nt = 0; nt < 2; ++nt) {
                    acc[mi][nt] = __builtin_amdgcn_mfma_f32_16x16x32_bf16(
                        pah, bh[nt], acc[mi][nt], 0, 0, 0);
                    acc[mi][nt] = __builtin_amdgcn_mfma_f32_16x16x32_bf16(
                        pah, bl[nt], acc[mi][nt], 0, 0, 0);
                    acc[mi][nt] = __builtin_amdgcn_mfma_f32_16x16x32_bf16(
                        pal, bh[nt], acc[mi][nt], 0, 0, 0);
                }
            }
        }
    }

    // ---- epilogue from MFMA acc layout: col=lr, row=lg*4+j ----
    constexpr float inv = 1.0f / (float)HEADS;
#pragma unroll
    for (int mi = 0; mi < 2; ++mi) {
#pragma unroll
        for (int nt = 0; nt < 2; ++nt) {
            int c_ = wn * 32 + nt * 16 + lr;
            float bs = bias[c_];
#pragma unroll
            for (int j = 0; j < 4; ++j) {
                int r_ = wm * 32 + mi * 16 + lg * 4 + j;
                size_t gi = (size_t)(g * 64 + r_) * 128 + c_;
                float v = acc[mi][nt][j] * inv + bs;
                if (EPI == 1) v = (v + hres[gi]) * 0.5f;
                hout[gi] = v;
            }
        }
    }
}

// ---------------- dense attention: one block per (graph, head) ----------------
__global__ __launch_bounds__(256, 3)
void attn_k(const float* __restrict__ q, const float* __restrict__ k,
            const float* __restrict__ v, float* __restrict__ o) {
    __shared__ __align__(16) float qT[32 * 68];
    __shared__ __align__(16) float kT[32 * 68];
    __shared__ __align__(16) float vs[64 * 36];
    __shared__ __align__(16) float St[64 * 68];
    __shared__ float rden[64];

    const int g = blockIdx.x >> 2, hh = blockIdx.x & 3;
    const int t = threadIdx.x;

#pragma unroll
    for (int i = 0; i < 2; ++i) {
        int f = t + i * 256;
        int row = f >> 3;
        int c4  = (f & 7) << 2;
        size_t gi = (size_t)(g * 64 + row) * 128 + hh * 32 + c4;
        float4 qv = *reinterpret_cast<const float4*>(&q[gi]);
        float4 kv = *reinterpret_cast<const float4*>(&k[gi]);
        float4 vv = *reinterpret_cast<const float4*>(&v[gi]);
        qT[(c4 + 0) * 68 + row] = qv.x; qT[(c4 + 1) * 68 + row] = qv.y;
        qT[(c4 + 2) * 68 + row] = qv.z; qT[(c4 + 3) * 68 + row] = qv.w;
        kT[(c4 + 0) * 68 + row] = kv.x; kT[(c4 + 1) * 68 + row] = kv.y;
        kT[(c4 + 2) * 68 + row] = kv.z; kT[(c4 + 3) * 68 + row] = kv.w;
        *reinterpret_cast<float4*>(&vs[row * 36 + c4]) = vv;
    }
    __syncthreads();

    {
        const int rg = (t & 15) << 2, cg = (t >> 4) << 2;
        float acc[4][4] = {};
#pragma unroll 8
        for (int kk = 0; kk < 32; ++kk) {
            float4 qv = *reinterpret_cast<const float4*>(&qT[kk * 68 + rg]);
            float4 kv = *reinterpret_cast<const float4*>(&kT[kk * 68 + cg]);
            acc[0][0] = fmaf(qv.x, kv.x, acc[0][0]);
            acc[0][1] = fmaf(qv.x, kv.y, acc[0][1]);
            acc[0][2] = fmaf(qv.x, kv.z, acc[0][2]);
            acc[0][3] = fmaf(qv.x, kv.w, acc[0][3]);
            acc[1][0] = fmaf(qv.y, kv.x, acc[1][0]);
            acc[1][1] = fmaf(qv.y, kv.y, acc[1][1]);
            acc[1][2] = fmaf(qv.y, kv.z, acc[1][2]);
            acc[1][3] = fmaf(qv.y, kv.w, acc[1][3]);
            acc[2][0] = fmaf(qv.z, kv.x, acc[2][0]);
            acc[2][1] = fmaf(qv.z, kv.y, acc[2][1]);
            acc[2][2] = fmaf(qv.z, kv.z, acc[2][2]);
            acc[2][3] = fmaf(qv.z, kv.w, acc[2][3]);
            acc[3][0] = fmaf(qv.w, kv.x, acc[3][0]);
            acc[3][1] = fmaf(qv.w, kv.y, acc[3][1]);
            acc[3][2] = fmaf(qv.w, kv.z, acc[3][2]);
            acc[3][3] = fmaf(qv.w, kv.w, acc[3][3]);
        }
        constexpr float sc = 0.17677669529663687f;
#pragma unroll
        for (int j = 0; j < 4; ++j) {
            float4 sv;
            sv.x = acc[0][j] * sc; sv.y = acc[1][j] * sc;
            sv.z = acc[2][j] * sc; sv.w = acc[3][j] * sc;
            *reinterpret_cast<float4*>(&St[(cg + j) * 68 + rg]) = sv;
        }
    }
    __syncthreads();

    {
        const int r = t >> 2, q4 = t & 3;
        float mx = -3.4e38f;
#pragma unroll
        for (int i = 0; i < 16; ++i)
            mx = fmaxf(mx, St[(q4 * 16 + i) * 68 + r]);
        mx = fmaxf(mx, __shfl_xor(mx, 1, 64));
        mx = fmaxf(mx, __shfl_xor(mx, 2, 64));
        float sm = 0.f;
#pragma unroll
        for (int i = 0; i < 16; ++i) {
            int idx = (q4 * 16 + i) * 68 + r;
            float e = __expf(St[idx] - mx);
            St[idx] = e;
            sm += e;
        }
        sm += __shfl_xor(sm, 1, 64);
        sm += __shfl_xor(sm, 2, 64);
        if (q4 == 0) rden[r] = 1.f / sm;
    }
    __syncthreads();

    {
        const int rg = (t & 15) << 2, dg = (t >> 4) << 1;
        float a0 = 0.f, a1 = 0.f, a2 = 0.f, a3 = 0.f;
        float b0 = 0.f, b1 = 0.f, b2 = 0.f, b3 = 0.f;
#pragma unroll 8
        for (int kk = 0; kk < 64; ++kk) {
            float4 pv = *reinterpret_cast<const float4*>(&St[kk * 68 + rg]);
            float2 vv = *reinterpret_cast<const float2*>(&vs[kk * 36 + dg]);
            a0 = fmaf(pv.x, vv.x, a0); b0 = fmaf(pv.x, vv.y, b0);
            a1 = fmaf(pv.y, vv.x, a1); b1 = fmaf(pv.y, vv.y, b1);
            a2 = fmaf(pv.z, vv.x, a2); b2 = fmaf(pv.z, vv.y, b2);
            a3 = fmaf(pv.w, vv.x, a3); b3 = fmaf(pv.w, vv.y, b3);
        }
        float4 rd = *reinterpret_cast<const float4*>(&rden[rg]);
        float2 o0 = {a0 * rd.x, b0 * rd.x};
        float2 o1 = {a1 * rd.y, b1 * rd.y};
        float2 o2 = {a2 * rd.z, b2 * rd.z};
        float2 o3 = {a3 * rd.w, b3 * rd.w};
        size_t gb = (size_t)(g * 64 + rg) * 128 + hh * 32 + dg;
        *reinterpret_cast<float2*>(&o[gb])       = o0;
        *reinterpret_cast<float2*>(&o[gb + 128]) = o1;
        *reinterpret_cast<float2*>(&o[gb + 256]) = o2;
        *reinterpret_cast<float2*>(&o[gb + 384]) = o3;
    }
}

// ---------------- launch ----------------
extern "C" void kernel_launch(void* const* d_in, const int* in_sizes, int n_in,
                              void* d_out, int out_size, void* d_ws, size_t ws_size,
                              hipStream_t stream) {
    const float* x     = (const float*)d_in[0];
    const int*   ei    = (const int*)d_in[1];
    const float* ea    = (const float*)d_in[2];
    const float* g0Wl  = (const float*)d_in[4];
    const float* g0Wr  = (const float*)d_in[5];
    const float* g0bl  = (const float*)d_in[6];
    const float* g0br  = (const float*)d_in[7];
    const float* g0We  = (const float*)d_in[8];
    const float* g0att = (const float*)d_in[9];
    const float* g0bias= (const float*)d_in[10];
    const float* gWl   = (const float*)d_in[11];
    const float* gWr   = (const float*)d_in[12];
    const float* gbl   = (const float*)d_in[13];
    const float* gbr   = (const float*)d_in[14];
    const float* gWe   = (const float*)d_in[15];
    const float* gatt  = (const float*)d_in[16];
    const float* gbias = (const float*)d_in[17];
    const float* Wq    = (const float*)d_in[18];
    const float* Wk    = (const float*)d_in[19];
    const float* Wv    = (const float*)d_in[20];
    const float* bq    = (const float*)d_in[21];
    const float* bk    = (const float*)d_in[22];
    const float* bv    = (const float*)d_in[23];
    const float* Wo    = (const float*)d_in[24];
    const float* bo    = (const float*)d_in[25];
    float* out = (float*)d_out;
    float* ws  = (float*)d_ws;

    float* h   = ws;                                   // Nn*128
    float* xlb = ws + (size_t)Nn * 128;                // CHUNK_N*512
    float* xrb = xlb + (size_t)CHUNK_N * 512;          // CHUNK_N*512
    float* qb = xlb;
    float* kb = xlb + (size_t)Nn * 128;
    float* vb = xrb;
    float* ob = xrb + (size_t)Nn * 128;
    unsigned short* whi = (unsigned short*)(xrb + (size_t)CHUNK_N * 512);
    unsigned short* wlo = whi + 458752;

    wprep<<<1792, 256, 0, stream>>>(gWl, gWr, Wq, Wk, Wv, Wo, whi, wlo);

    // ---- layer 0 (heads=1, concat) ----
    proj0<<<Nn * 128 / 256, 256, 0, stream>>>(x, g0Wl, g0Wr, g0bl, g0br, xlb, xrb);
    gat_edge<1, 0><<<Bg, 512, 0, stream>>>(xlb, xrb, ei, ea, g0We, g0att,
                                           g0bias, nullptr, h, 0);

    // ---- layers 1..3 (heads=4, mean, residual) ----
    for (int i = 0; i < 3; ++i) {
        for (int c = 0; c < 2; ++c) {
            const float* Ain = h + (size_t)c * CHUNK_N * 128;
            dim3 grid(512 / 128, CHUNK_N / 128);
            gemm_mfma<true, 0><<<grid, 256, 0, stream>>>(
                Ain, whi + (size_t)(2 * i) * 65536, wlo + (size_t)(2 * i) * 65536,
                gbl + i * 512, nullptr, xlb, 512);
            gemm_mfma<true, 0><<<grid, 256, 0, stream>>>(
                Ain, whi + (size_t)(2 * i + 1) * 65536, wlo + (size_t)(2 * i + 1) * 65536,
                gbr + i * 512, nullptr, xrb, 512);
            gat_edge<4, 1><<<CHUNK_G, 512, 0, stream>>>(
                xlb, xrb, ei, ea, gWe + (size_t)i * 3 * 512,
                gatt + (size_t)i * 4 * 128, gbias + i * 128, h, h, c * CHUNK_G);
        }
    }

    // ---- dense attention over graphs ----
    {
        dim3 grid(1, Nn / 128);
        gemm_mfma<false, 0><<<grid, 256, 0, stream>>>(h, whi + 393216, wlo + 393216,
                                                      bq, nullptr, qb, 128);
        gemm_mfma<false, 0><<<grid, 256, 0, stream>>>(h, whi + 409600, wlo + 409600,
                                                      bk, nullptr, kb, 128);
        gemm_mfma<false, 0><<<grid, 256, 0, stream>>>(h, whi + 425984, wlo + 425984,
                                                      bv, nullptr, vb, 128);
        attn_k<<<Bg * NH, 256, 0, stream>>>(qb, kb, vb, ob);
        gemm_mfma<false, 1><<<grid, 256, 0, stream>>>(ob, whi + 442368, wlo + 442368,
                                                      bo, h, out, 128);
    }
}